// Round 1
// baseline (425.579 us; speedup 1.0000x reference)
//
#include <hip/hip_runtime.h>

// Problem constants (from reference setup_inputs)
#define B_   4
#define T_   1024
#define E_   4
#define C_   512
#define IN_  2048
#define OUT_ 8192
#define EI_  512   // expert in-features = IN_/E_

typedef float f32x4 __attribute__((ext_vector_type(4)));
typedef __bf16 bf16x8 __attribute__((ext_vector_type(8)));
typedef unsigned short ushort8 __attribute__((ext_vector_type(8)));

__device__ __forceinline__ unsigned short f32_bf16(float f) {
  unsigned int u = __float_as_uint(f);
  u += 0x7FFFu + ((u >> 16) & 1u);   // round-to-nearest-even (finite inputs)
  return (unsigned short)(u >> 16);
}

__device__ __forceinline__ void gl2lds16(const void* g, void* l) {
  __builtin_amdgcn_global_load_lds(
      (const __attribute__((address_space(1))) void*)g,
      (__attribute__((address_space(3))) void*)l, 16, 0, 0);
}

// ---------------------------------------------------------------------------
// Transpose-convert: src (B, T, 2048) fp32  ->  dst (B, E=4, 512, T) bf16.
// ---------------------------------------------------------------------------
__global__ __launch_bounds__(256)
void transpose_cvt(const float* __restrict__ src, unsigned short* __restrict__ dst) {
  __shared__ float tile[64][68];
  const int b = blockIdx.z;
  const int k0 = blockIdx.x * 64;
  const int t0 = blockIdx.y * 64;
  const int u = threadIdx.x;
  const int lrow = u >> 4;
  const int lcol = (u & 15) * 4;
  const float* s = src + (size_t)b * (T_ * 2048) + (size_t)t0 * 2048 + k0;
#pragma unroll
  for (int r = 0; r < 4; r++) {
    float4 v = *(const float4*)(s + (size_t)(lrow + 16 * r) * 2048 + lcol);
    tile[lrow + 16 * r][lcol]     = v.x;
    tile[lrow + 16 * r][lcol + 1] = v.y;
    tile[lrow + 16 * r][lcol + 2] = v.z;
    tile[lrow + 16 * r][lcol + 3] = v.w;
  }
  __syncthreads();
  const int w = u >> 6, lane = u & 63;
  const int kg = k0 + lane;
  const int e  = kg >> 9;
  const int kl = kg & 511;
  unsigned short* d = dst + (((size_t)b * 4 + e) * 512 + kl) * 1024 + t0 + w * 16;
#pragma unroll
  for (int s8 = 0; s8 < 2; s8++) {
    const int tt = w * 16 + s8 * 8;
    ushort8 r;
#pragma unroll
    for (int j = 0; j < 8; j++) r[j] = f32_bf16(tile[tt + j][lane]);
    *(ushort8*)(d + s8 * 8) = r;
  }
}

// ---------------------------------------------------------------------------
// combine (B,T,E,C) fp32 -> bf16, plus row-sum S[b,t]
// ---------------------------------------------------------------------------
__global__ __launch_bounds__(256)
void cvt_combine_rowsum(const float* __restrict__ in,
                        unsigned short* __restrict__ out,
                        float* __restrict__ S) {
  const int row = blockIdx.x;
  const int u = threadIdx.x;
  const float4* p = (const float4*)(in + (size_t)row * 2048) + (size_t)u * 2;
  float4 a = p[0], b = p[1];
  ushort8 r;
  r[0] = f32_bf16(a.x); r[1] = f32_bf16(a.y);
  r[2] = f32_bf16(a.z); r[3] = f32_bf16(a.w);
  r[4] = f32_bf16(b.x); r[5] = f32_bf16(b.y);
  r[6] = f32_bf16(b.z); r[7] = f32_bf16(b.w);
  *((ushort8*)(out + (size_t)row * 2048) + u) = r;
  float s = (a.x + a.y + a.z + a.w) + (b.x + b.y + b.z + b.w);
  __shared__ float red[256];
  red[u] = s;
  __syncthreads();
#pragma unroll
  for (int st = 128; st > 0; st >>= 1) {
    if (u < st) red[u] += red[u + st];
    __syncthreads();
  }
  if (u == 0) S[row] = red[0];
}

// ---------------------------------------------------------------------------
// weight permute: w[e,o,i] -> W2[o, e*512+i] bf16
// ---------------------------------------------------------------------------
__global__ __launch_bounds__(256)
void permute_w(const float* __restrict__ weight, unsigned short* __restrict__ W2) {
  const int tid = blockIdx.x * 256 + threadIdx.x;
  const int i8 = tid & 63;
  const int e  = (tid >> 6) & 3;
  const int o  = tid >> 8;
  const float* s = weight + (size_t)e * 4194304 + (size_t)o * 512 + i8 * 8;
  float4 a = *(const float4*)s;
  float4 b = *(const float4*)(s + 4);
  ushort8 r;
  r[0] = f32_bf16(a.x); r[1] = f32_bf16(a.y);
  r[2] = f32_bf16(a.z); r[3] = f32_bf16(a.w);
  r[4] = f32_bf16(b.x); r[5] = f32_bf16(b.y);
  r[6] = f32_bf16(b.z); r[7] = f32_bf16(b.w);
  *(ushort8*)(W2 + (size_t)o * 2048 + e * 512 + i8 * 8) = r;
}

// ---------------------------------------------------------------------------
// gemm_bt (m97 structure, 128x128 tile): used for the two small GEMMs.
// ---------------------------------------------------------------------------
template <int MODE>
__global__ __launch_bounds__(256, 2)
void gemm_bt(const unsigned short* __restrict__ A,
             const unsigned short* __restrict__ Bm,
             void* __restrict__ Out, const float* __restrict__ bias,
             const float* __restrict__ S,
             int lda, int ldb, int ldo, int K, int Ediv,
             long sAb, long sAe, long sBb, long sBe, long sOb, long sOe) {
  __shared__ __align__(16) unsigned short As[128 * 32];
  __shared__ __align__(16) unsigned short Bs[128 * 32];
  const int u = threadIdx.x;
  const int z = blockIdx.z;
  const int zb = z / Ediv, ze = z % Ediv;
  const unsigned short* Ab = A  + zb * sAb + ze * sAe + (long)(blockIdx.y * 128) * lda;
  const unsigned short* Bb = Bm + zb * sBb + ze * sBe + (long)(blockIdx.x * 128) * ldb;

  const int srow = u >> 2;
  const int scol = (u & 3) * 8;
  const unsigned short* ga0 = Ab + (long)srow * lda + scol;
  const unsigned short* ga1 = ga0 + (long)64 * lda;
  const unsigned short* gb0 = Bb + (long)srow * ldb + scol;
  const unsigned short* gb1 = gb0 + (long)64 * ldb;

  const int w = u >> 6, lane = u & 63;
  unsigned short* la0 = As + w * 512;
  unsigned short* la1 = la0 + 2048;
  unsigned short* lb0 = Bs + w * 512;
  unsigned short* lb1 = lb0 + 2048;

  const int wm = (w & 1) * 64, wn = (w >> 1) * 64;
  const int fm = lane & 15, fk = (lane >> 4) * 8;
  const unsigned short* pA = As + (wm + fm) * 32 + fk;
  const unsigned short* pB = Bs + (wn + fm) * 32 + fk;

  f32x4 acc[4][4] = {};

  for (int kt = 0; kt < K; kt += 32) {
    __syncthreads();
    gl2lds16(ga0, la0);
    gl2lds16(ga1, la1);
    gl2lds16(gb0, lb0);
    gl2lds16(gb1, lb1);
    ga0 += 32; ga1 += 32; gb0 += 32; gb1 += 32;
    __syncthreads();
    bf16x8 af[4], bfv[4];
#pragma unroll
    for (int i = 0; i < 4; i++) {
      af[i]  = *(const bf16x8*)(pA + i * 16 * 32);
      bfv[i] = *(const bf16x8*)(pB + i * 16 * 32);
    }
#pragma unroll
    for (int i = 0; i < 4; i++)
#pragma unroll
      for (int j = 0; j < 4; j++)
        acc[i][j] = __builtin_amdgcn_mfma_f32_16x16x32_bf16(af[i], bfv[j],
                                                            acc[i][j], 0, 0, 0);
  }

  const long ob = zb * sOb + ze * sOe;
  const int em0 = blockIdx.y * 128 + wm + ((lane >> 4) << 2);
  const int en0 = blockIdx.x * 128 + wn + (lane & 15);
  float bcol[4];
  if (MODE == 1) {
#pragma unroll
    for (int j = 0; j < 4; j++) bcol[j] = bias[en0 + j * 16];
  }
#pragma unroll
  for (int i = 0; i < 4; i++)
#pragma unroll
    for (int r = 0; r < 4; r++) {
      const int m = em0 + i * 16 + r;
      const float sm = (MODE == 1) ? S[m] : 0.0f;
#pragma unroll
      for (int j = 0; j < 4; j++) {
        const long off = ob + (long)m * ldo + en0 + j * 16;
        if (MODE == 1)
          ((float*)Out)[off] = acc[i][j][r] + sm * bcol[j];
        else
          ((unsigned short*)Out)[off] = f32_bf16(acc[i][j][r]);
      }
    }
}

// ---------------------------------------------------------------------------
// gemm256: 256x256 tile, BK=64, 8 waves, 8-phase schedule (T1+T2+T3+T4+T5).
// D[m,n] = sum_k A[m,k]*B[n,k] + S[m]*bias[n].  M=4096 N=8192 K=2048.
//
// LDS (128 KiB): A buf0 [0,32K) | A buf1 [32K,64K) | B buf0 [64K,96K) | B buf1 [96K,128K)
// Tile layout [256 rows][64 k] bf16, XOR-swizzled: byte ^= ((row&7)<<4).
// global_load_lds writes LINEAR; inverse swizzle folded into per-lane global src.
//
// Pipeline (per K-tile kt, buffer bb=kt&1; 4 phases, each: ds_read | 1 half-tile
// stage | barrier | lgkmcnt(0) | 16 MFMA | barrier):
//   p0: read A[mh0](8)+B[nh0](4); stage B0(kt+1)->nb ; MFMA (mh0 x nh0)
//   p1: read A[mh1](8)          ; stage B1(kt+1)->nb ; MFMA (mh1 x nh0)
//   p2: read B[nh1](4)          ; stage A0(kt+2)->bb ; MFMA (mh0 x nh1)
//   p3:                           stage A1(kt+2)->bb ; MFMA (mh1 x nh1); vmcnt(4)
// Slot safety: A slots dead after p1 (stage at p2/p3 OK); B stages go to nb.
// vmcnt(4) keeps A0,A1(kt+2) in flight across the barrier (counted, never 0).
// Tail: kt+1/kt+2 clamped to 31 -> restages identical bytes (benign).
// ---------------------------------------------------------------------------
#define DSR(dst, addr) do { f32x4 _t_; \
    asm volatile("ds_read_b128 %0, %1" : "=v"(_t_) : "v"(addr)); \
    dst = __builtin_bit_cast(bf16x8, _t_); } while (0)

__global__ __launch_bounds__(512, 2)
void gemm256(const unsigned short* __restrict__ A,
             const unsigned short* __restrict__ Bm,
             float* __restrict__ Out,
             const float* __restrict__ bias,
             const float* __restrict__ S) {
  __shared__ __align__(16) unsigned short lds[65536];  // 128 KiB
  char* ldsg = (char*)lds;
  const unsigned ldsb =
      (unsigned)(unsigned long long)(__attribute__((address_space(3))) char*)(void*)lds;

  int wg = blockIdx.x;
  wg = (wg & 7) * 64 + (wg >> 3);      // bijective XCD swizzle (512 % 8 == 0)
  const int bx = wg & 31;              // N tile (8192/256)
  const int by = wg >> 5;              // M tile (4096/256)

  const int u = threadIdx.x;
  const int w = u >> 6, lane = u & 63;
  const unsigned w1024 = (unsigned)(w * 1024);
  const int wmw = (w >> 2) * 128;      // wave M offset in tile
  const int wnw = (w & 3) * 64;        // wave N offset in tile
  const int fm = lane & 15;

  // read-side swizzled column bases (byte ^= ((row&7)<<4); row&7 == fm&7)
  const unsigned hi16  = (unsigned)(((lane >> 4) & 3) * 16);
  const unsigned xorv  = (unsigned)((fm & 7) << 4);
  const unsigned colS0 = hi16 ^ xorv;
  const unsigned aR0 = (unsigned)((wmw + fm) * 128) + colS0;
  const unsigned aR1 = aR0 ^ 64u;                     // k-step 1 (+32 elems)
  const unsigned bR0 = 65536u + (unsigned)((wnw + fm) * 128) + colS0;
  const unsigned bR1 = bR0 ^ 64u;

  // stage-side: LDS dest linear (u*16B within half-tile); source pre-swizzled.
  // lane's row within (h,c) subgroup = w*8 + (lane>>3); src col = cb ^ ((row&7)<<4)
  const int srr = w * 8 + (lane >> 3);
  const unsigned swzS = (unsigned)((((lane & 7) ^ ((lane >> 3) & 7)) << 4));
  const char* gA = (const char*)(A  + (size_t)(by * 256) * 2048) + (size_t)srr * 4096 + swzS;
  const char* gB = (const char*)(Bm + (size_t)(bx * 256) * 2048) + (size_t)srr * 4096 + swzS;

  // one STG = one half-tile (128 rows x 128B): 2 x global_load_lds dwordx4 / thread
#define STG(gsrc, loff) do { \
    gl2lds16((gsrc), ldsg + (loff)); \
    gl2lds16((gsrc) + 262144, ldsg + (loff) + 8192); } while (0)

  // prologue: kt0 {A0,A1,B0,B1} -> buf0; kt1 {A0,A1} -> buf1; wait kt0 landed
  STG(gA,                    0u + w1024);
  STG(gA + 524288,       16384u + w1024);
  STG(gB,                65536u + w1024);
  STG(gB + 524288,       81920u + w1024);
  STG(gA + 128,          32768u + w1024);
  STG(gA + 128 + 524288, 49152u + w1024);
  asm volatile("s_waitcnt vmcnt(4)" ::: "memory");
  __builtin_amdgcn_s_barrier();

  f32x4 acc[8][4] = {};
  bf16x8 a0[4][2], a1[4][2], bq[2][2];

  for (int kt = 0; kt < 32; ++kt) {
    const unsigned bbO = (unsigned)((kt & 1) * 32768);
    const unsigned nbR = bbO ^ 32768u;
    const int ktB = (kt + 1 < 32) ? kt + 1 : 31;
    const int ktA = (kt + 2 < 32) ? kt + 2 : 31;
    const char* gBn = gB + ktB * 128;
    const char* gAn = gA + ktA * 128;

    // -------- phase 0: A[mh0] + B[nh0] reads; stage B0(kt+1); MFMA mh0 x nh0
#pragma unroll
    for (int i = 0; i < 4; ++i) {
      DSR(a0[i][0], ldsb + bbO + aR0 + (unsigned)(i * 2048));
      DSR(a0[i][1], ldsb + bbO + aR1 + (unsigned)(i * 2048));
    }
#pragma unroll
    for (int j = 0; j < 2; ++j) {
      DSR(bq[j][0], ldsb + bbO + bR0 + (unsigned)(j * 2048));
      DSR(bq[j][1], ldsb + bbO + bR1 + (unsigned)(j * 2048));
    }
    STG(gBn, 65536u + nbR + w1024);
    __builtin_amdgcn_s_barrier();
    asm volatile("s_waitcnt lgkmcnt(0)" ::: "memory");
    __builtin_amdgcn_sched_barrier(0);
    __builtin_amdgcn_s_setprio(1);
#pragma unroll
    for (int i = 0; i < 4; ++i)
#pragma unroll
      for (int j = 0; j < 2; ++j) {
        acc[i][j] = __builtin_amdgcn_mfma_f32_16x16x32_bf16(a0[i][0], bq[j][0], acc[i][j], 0, 0, 0);
        acc[i][j] = __builtin_amdgcn_mfma_f32_16x16x32_bf16(a0[i][1], bq[j][1], acc[i][j], 0, 0, 0);
      }
    __builtin_amdgcn_s_setprio(0);
    __builtin_amdgcn_s_barrier();

    // -------- phase 1: A[mh1] reads; stage B1(kt+1); MFMA mh1 x nh0
#pragma unroll
    for (int i = 0; i < 4; ++i) {
      DSR(a1[i][0], ldsb + bbO + aR0 + (unsigned)((4 + i) * 2048));
      DSR(a1[i][1], ldsb + bbO + aR1 + (unsigned)((4 + i) * 2048));
    }
    STG(gBn + 524288, 81920u + nbR + w1024);
    __builtin_amdgcn_s_barrier();
    asm volatile("s_waitcnt lgkmcnt(0)" ::: "memory");
    __builtin_amdgcn_sched_barrier(0);
    __builtin_amdgcn_s_setprio(1);
#pragma unroll
    for (int i = 0; i < 4; ++i)
#pragma unroll
      for (int j = 0; j < 2; ++j) {
        acc[4 + i][j] = __builtin_amdgcn_mfma_f32_16x16x32_bf16(a1[i][0], bq[j][0], acc[4 + i][j], 0, 0, 0);
        acc[4 + i][j] = __builtin_amdgcn_mfma_f32_16x16x32_bf16(a1[i][1], bq[j][1], acc[4 + i][j], 0, 0, 0);
      }
    __builtin_amdgcn_s_setprio(0);
    __builtin_amdgcn_s_barrier();

    // -------- phase 2: B[nh1] reads (reuse bq); stage A0(kt+2); MFMA mh0 x nh1
#pragma unroll
    for (int j = 0; j < 2; ++j) {
      DSR(bq[j][0], ldsb + bbO + bR0 + (unsigned)((2 + j) * 2048));
      DSR(bq[j][1], ldsb + bbO + bR1 + (unsigned)((2 + j) * 2048));
    }
    STG(gAn, bbO + w1024);
    __builtin_amdgcn_s_barrier();
    asm volatile("s_waitcnt lgkmcnt(0)" ::: "memory");
    __builtin_amdgcn_sched_barrier(0);
    __builtin_amdgcn_s_setprio(1);
#pragma unroll
    for (int i = 0; i < 4; ++i)
#pragma unroll
      for (int j = 0; j < 2; ++j) {
        acc[i][2 + j] = __builtin_amdgcn_mfma_f32_16x16x32_bf16(a0[i][0], bq[j][0], acc[i][2 + j], 0, 0, 0);
        acc[i][2 + j] = __builtin_amdgcn_mfma_f32_16x16x32_bf16(a0[i][1], bq[j][1], acc[i][2 + j], 0, 0, 0);
      }
    __builtin_amdgcn_s_setprio(0);
    __builtin_amdgcn_s_barrier();

    // -------- phase 3: stage A1(kt+2); MFMA mh1 x nh1; counted vmcnt(4)
    STG(gAn + 524288, bbO + 16384u + w1024);
    __builtin_amdgcn_s_barrier();
    __builtin_amdgcn_s_setprio(1);
#pragma unroll
    for (int i = 0; i < 4; ++i)
#pragma unroll
      for (int j = 0; j < 2; ++j) {
        acc[4 + i][2 + j] = __builtin_amdgcn_mfma_f32_16x16x32_bf16(a1[i][0], bq[j][0], acc[4 + i][2 + j], 0, 0, 0);
        acc[4 + i][2 + j] = __builtin_amdgcn_mfma_f32_16x16x32_bf16(a1[i][1], bq[j][1], acc[4 + i][2 + j], 0, 0, 0);
      }
    __builtin_amdgcn_s_setprio(0);
    asm volatile("s_waitcnt vmcnt(4)" ::: "memory");
    __builtin_amdgcn_sched_barrier(0);
    __builtin_amdgcn_s_barrier();
  }
#undef STG

  // epilogue: C/D layout col=lane&15, row=(lane>>4)*4+reg  [m89/m91]
  const int m0 = by * 256 + wmw + ((lane >> 4) << 2);
  const int n0 = bx * 256 + wnw + (lane & 15);
  float bc[4];
#pragma unroll
  for (int j = 0; j < 4; ++j) bc[j] = bias[n0 + j * 16];
#pragma unroll
  for (int i = 0; i < 8; ++i)
#pragma unroll
    for (int r = 0; r < 4; ++r) {
      const int m = m0 + i * 16 + r;
      const float sm = S[m];
#pragma unroll
      for (int j = 0; j < 4; ++j)
        Out[(size_t)m * 8192 + n0 + j * 16] = acc[i][j][r] + sm * bc[j];
    }
}

// ---------------------------------------------------------------------------
// launch
// ---------------------------------------------------------------------------
extern "C" void kernel_launch(void* const* d_in, const int* in_sizes, int n_in,
                              void* d_out, int out_size, void* d_ws,
                              size_t ws_size, hipStream_t stream) {
  (void)in_sizes; (void)n_in; (void)out_size; (void)ws_size;
  const float* x       = (const float*)d_in[0];  // (B,T,IN)
  const float* combine = (const float*)d_in[1];  // (B,T,E,C)
  const float* mask    = (const float*)d_in[2];  // (B,T,E,C)
  const float* weight  = (const float*)d_in[3];  // (OUT,IN)
  const float* bias    = (const float*)d_in[4];  // (OUT,)
  float* out = (float*)d_out;                    // (B,T,OUT) fp32

  // workspace layout (~105 MB)
  char* ws = (char*)d_ws;
  unsigned short* W2      = (unsigned short*)ws;                    // 32 MB
  unsigned short* comb_bf = (unsigned short*)(ws + 33554432);       // 16 MB
  float*          S       = (float*)(ws + 50331648);                // 16 KB
  unsigned short* xT      = (unsigned short*)(ws + 51380224);       // 16 MB
  unsigned short* maskT   = (unsigned short*)(ws + 68157440);       // 16 MB
  unsigned short* xdT     = (unsigned short*)(ws + 84934656);       //  8 MB
  unsigned short* zbuf    = (unsigned short*)(ws + 93323264);       // 16 MB

  // 0) layout/dtype prep
  transpose_cvt<<<dim3(32, 16, 4), 256, 0, stream>>>(x, xT);        // xT[b,e,i,t]
  transpose_cvt<<<dim3(32, 16, 4), 256, 0, stream>>>(mask, maskT);  // maskT[b,e,c,t]
  cvt_combine_rowsum<<<4096, 256, 0, stream>>>(combine, comb_bf, S);
  permute_w<<<8192, 256, 0, stream>>>(weight, W2);                  // W2[o,(e,i)]

  // 1) xdT[b,e,i,c] = sum_t xT[b,e,i,t] * maskT[b,e,c,t]
  gemm_bt<0><<<dim3(4, 4, 16), 256, 0, stream>>>(
      xT, maskT, (void*)xdT, nullptr, nullptr, 1024, 1024, 512, 1024,
      4, 2097152L, 524288L, 2097152L, 524288L, 1048576L, 262144L);

  // 2) z[b,t,(e,i)] = sum_c comb_bf[b,t,e,c] * xdT[b,e,i,c]
  gemm_bt<0><<<dim3(4, 8, 16), 256, 0, stream>>>(
      comb_bf, xdT, (void*)zbuf, nullptr, nullptr, 2048, 512, 2048, 512,
      4, 2097152L, 512L, 1048576L, 262144L, 2097152L, 512L);

  // 3) out[m,o] = sum_{(e,i)} z[m,(e,i)] * W2[o,(e,i)] + S[m]*bias[o]
  //    M=4096 N=8192 K=2048 — 256^2 8-phase kernel
  gemm256<<<dim3(512), 512, 0, stream>>>(zbuf, W2, out, bias, S);
}